// Round 1
// 524.601 us; speedup vs baseline: 1.2747x; 1.2747x over previous
//
#include <hip/hip_runtime.h>
#include <cstdint>
#include <cstddef>

// Problem constants
#define NN 128   // seq len
#define BB 8     // batch
#define EE 256   // embed
#define HH 256   // hidden
#define SS 256   // segment dim
#define TT 32    // segment threshold
#define G3 768   // 3*H = 3*S
#define HBSTR 264           // LDS bf16 h row stride (pad 256->264)
#define HIDOFF 33816576ull  // 8256*8*512, start of `hidden` in d_out (elements)
#define OUT_ELEMS 33820672ull

typedef __attribute__((ext_vector_type(8))) short bf16x8;
typedef __attribute__((ext_vector_type(4))) float f32x4;

__device__ __forceinline__ float bf2f(unsigned short u) {
    union { unsigned u; float f; } v; v.u = ((unsigned)u) << 16; return v.f;
}
__device__ __forceinline__ unsigned short f2bf(float f) {
    union { float f; unsigned u; } v; v.f = f;
    unsigned r = v.u + 0x7fffu + ((v.u >> 16) & 1u);   // RNE
    return (unsigned short)(r >> 16);
}
__device__ __forceinline__ float rcpf(float x) { return __builtin_amdgcn_rcpf(x); }
__device__ __forceinline__ float sigm(float x) { return rcpf(1.f + __expf(-x)); }
__device__ __forceinline__ float tanh_fast(float x) {
    float xc = fminf(fmaxf(x, -10.f), 10.f);
    float e2 = __expf(2.f * xc);
    return (e2 - 1.f) * rcpf(e2 + 1.f);
}

// fp32-vs-bf16 physical layout detector (round-2 counters: fp32 confirmed).
__device__ __forceinline__ int detect_f32(const void* emb) {
    const unsigned* w = (const unsigned*)emb;
    int bad = 0;
    for (int i = 0; i < 128; ++i) {
        unsigned u = w[i];
        bad |= (((u >> 7)  & 0xFFu) >= 0xC8u);
        bad |= (((u >> 23) & 0xFFu) >= 0xC8u);
    }
    return bad;
}
__device__ __forceinline__ float lds1(const void* p, size_t i, int f32) {
    return f32 ? ((const float*)p)[i] : bf2f(((const unsigned short*)p)[i]);
}
__device__ __forceinline__ void outw(void* p, size_t i, float v, int f32) {
    if (f32) ((float*)p)[i] = v;
    else ((unsigned short*)p)[i] = f2bf(v);
}

// ---------------------------------------------------------------------------
// One-shot weight conversion to bf16 in ws. Layout (ushort offsets):
// Wi_f 0, Wi_r 196608, Wh_f 393216, Wh_r 589824, Wh_s 786432, Wi_s 983040 (x393216)
__global__ __launch_bounds__(256) void conv_all(
    const void* __restrict__ Wi_f, const void* __restrict__ Wi_r,
    const void* __restrict__ Wh_f, const void* __restrict__ Wh_r,
    const void* __restrict__ Wh_s, const void* __restrict__ Wi_s,
    unsigned short* __restrict__ dst, const void* __restrict__ emb) {
    const int f32 = detect_f32(emb);
    size_t i = ((size_t)blockIdx.x * 256 + threadIdx.x) * 8;   // grid 672 blocks
    const void* src; size_t off;
    if      (i < 196608)  { src = Wi_f; off = i; }
    else if (i < 393216)  { src = Wi_r; off = i - 196608; }
    else if (i < 589824)  { src = Wh_f; off = i - 393216; }
    else if (i < 786432)  { src = Wh_r; off = i - 589824; }
    else if (i < 983040)  { src = Wh_s; off = i - 786432; }
    else                  { src = Wi_s; off = i - 983040; }
    bf16x8 v;
    if (f32) {
        const float* q = (const float*)src + off;
        float4 a = *(const float4*)q, b = *(const float4*)(q + 4);
        v[0] = (short)f2bf(a.x); v[1] = (short)f2bf(a.y);
        v[2] = (short)f2bf(a.z); v[3] = (short)f2bf(a.w);
        v[4] = (short)f2bf(b.x); v[5] = (short)f2bf(b.y);
        v[6] = (short)f2bf(b.z); v[7] = (short)f2bf(b.w);
    } else {
        v = *(const bf16x8*)((const unsigned short*)src + off);
    }
    *(bf16x8*)(dst + i) = v;
}

// ---------------------------------------------------------------------------
// MFMA GEMM, W pre-converted bf16. C bf16. A: token-gather (emb) or bf16 ws.
template <int KK>
__global__ __launch_bounds__(256) void gemm_mfma(
    const int* __restrict__ tok, const void* __restrict__ Asrc,
    const unsigned short* __restrict__ W,  const void* __restrict__ bias,
    unsigned short* __restrict__ C,
    const unsigned short* __restrict__ W2, const void* __restrict__ bias2,
    unsigned short* __restrict__ C2, const void* __restrict__ emb) {

    const int f32 = detect_f32(emb);
    __shared__ unsigned short As[64 * 260];

    int bid = blockIdx.x;
    const unsigned short* Wp = W; const void* bp = bias; unsigned short* Cp = C;
    if (C2 && bid >= 128) { bid -= 128; Wp = W2; bp = bias2; Cp = C2; }
    const int mb = bid >> 3, nb = bid & 7;

    const int tid = threadIdx.x, wave = tid >> 6, lane = tid & 63;
    const int l15 = lane & 15, quad = lane >> 4;

    f32x4 acc[6];
#pragma unroll
    for (int nt = 0; nt < 6; ++nt) acc[nt] = (f32x4){0.f, 0.f, 0.f, 0.f};

    for (int kh = 0; kh < KK; kh += 256) {
        __syncthreads();
        for (int e = tid * 4; e < 64 * 256; e += 1024) {
            int r = e >> 8, k = e & 255;
            int gr = mb * 64 + r;
            unsigned short h4[4];
            if (tok) {
                size_t arow = (size_t)tok[gr] * EE + kh + k;
                if (f32) {
                    float4 v = *(const float4*)((const float*)Asrc + arow);
                    h4[0] = f2bf(v.x); h4[1] = f2bf(v.y); h4[2] = f2bf(v.z); h4[3] = f2bf(v.w);
                } else {
                    *(uint2*)h4 = *(const uint2*)((const unsigned short*)Asrc + arow);
                }
            } else {
                *(uint2*)h4 = *(const uint2*)((const unsigned short*)Asrc + (size_t)gr * KK + kh + k);
            }
            *(uint2*)(As + r * 260 + k) = *(uint2*)h4;
        }
        __syncthreads();
#pragma unroll
        for (int kt = 0; kt < 8; ++kt) {
            bf16x8 Af = *(const bf16x8*)(As + (wave * 16 + l15) * 260 + kt * 32 + quad * 8);
#pragma unroll
            for (int nt = 0; nt < 6; ++nt) {
                int col = nb * 96 + nt * 16 + l15;
                bf16x8 Bfr = *(const bf16x8*)(Wp + (size_t)col * KK + kh + kt * 32 + quad * 8);
                acc[nt] = __builtin_amdgcn_mfma_f32_16x16x32_bf16(Af, Bfr, acc[nt], 0, 0, 0);
            }
        }
    }
#pragma unroll
    for (int nt = 0; nt < 6; ++nt) {
        int col = nb * 96 + nt * 16 + l15;
        float bv = lds1(bp, col, f32);
#pragma unroll
        for (int r4 = 0; r4 < 4; ++r4) {
            int row = mb * 64 + wave * 16 + quad * 4 + r4;
            Cp[(size_t)row * G3 + col] = f2bf(acc[nt][r4] + bv);
        }
    }
}

// ---------------------------------------------------------------------------
// Scan machinery (round-4 proven config): 256 thr / 4 waves, 1 wave/EU.
// Each wave owns 192 cols: 96 B-frags = 64 AGPR-pinned + 32 VGPR-pinned.
#define LOAD_BFRAGS(Whc)                                                        \
    bf16x8 Ba[8][8]; bf16x8 Bv[8][4];                                           \
    _Pragma("unroll")                                                           \
    for (int nt = 0; nt < 12; ++nt) {                                           \
        int col = wave * 192 + nt * 16 + l15;                                   \
        _Pragma("unroll")                                                       \
        for (int kt = 0; kt < 8; ++kt) {                                        \
            bf16x8 f = *(const bf16x8*)(Whc + (size_t)col * 256 + kt * 32 + quad * 8); \
            if (nt < 8) Ba[kt][nt] = f; else Bv[kt][nt - 8] = f;                \
        }                                                                       \
    }                                                                           \
    _Pragma("unroll")                                                           \
    for (int kt = 0; kt < 8; ++kt) {                                            \
        _Pragma("unroll")                                                       \
        for (int nt = 0; nt < 8; ++nt) asm volatile("" : "+a"(Ba[kt][nt]));     \
        _Pragma("unroll")                                                       \
        for (int nt = 0; nt < 4; ++nt) asm volatile("" : "+v"(Bv[kt][nt]));     \
    }

// Full 8-batch variant (seg_scan): writes gh rows 0..7.
#define MFMA_GH()                                                               \
    {                                                                           \
        f32x4 acc[12];                                                          \
        _Pragma("unroll")                                                       \
        for (int nt = 0; nt < 12; ++nt) acc[nt] = (f32x4){0.f, 0.f, 0.f, 0.f};  \
        _Pragma("unroll")                                                       \
        for (int kt = 0; kt < 8; ++kt) {                                        \
            bf16x8 Af = *(const bf16x8*)(hb + l15 * HBSTR + kt * 32 + quad * 8);\
            _Pragma("unroll")                                                   \
            for (int nt = 0; nt < 8; ++nt)                                      \
                acc[nt] = __builtin_amdgcn_mfma_f32_16x16x32_bf16(Af, Ba[kt][nt], acc[nt], 0, 0, 0); \
            _Pragma("unroll")                                                   \
            for (int nt = 0; nt < 4; ++nt)                                      \
                acc[8 + nt] = __builtin_amdgcn_mfma_f32_16x16x32_bf16(Af, Bv[kt][nt], acc[8 + nt], 0, 0, 0); \
        }                                                                       \
        if (quad < 2) {                                                         \
            _Pragma("unroll")                                                   \
            for (int nt = 0; nt < 12; ++nt) {                                   \
                int col = wave * 192 + nt * 16 + l15;                           \
                _Pragma("unroll")                                               \
                for (int r4 = 0; r4 < 4; ++r4) gh[quad * 4 + r4][col] = acc[nt][r4]; \
            }                                                                   \
        }                                                                       \
    }

// Single-batch variant (token scan, batch-split): only C row 0 is live.
#define MFMA_GH_ROW0()                                                          \
    {                                                                           \
        f32x4 acc[12];                                                          \
        _Pragma("unroll")                                                       \
        for (int nt = 0; nt < 12; ++nt) acc[nt] = (f32x4){0.f, 0.f, 0.f, 0.f};  \
        _Pragma("unroll")                                                       \
        for (int kt = 0; kt < 8; ++kt) {                                        \
            bf16x8 Af = *(const bf16x8*)(hb + l15 * HBSTR + kt * 32 + quad * 8);\
            _Pragma("unroll")                                                   \
            for (int nt = 0; nt < 8; ++nt)                                      \
                acc[nt] = __builtin_amdgcn_mfma_f32_16x16x32_bf16(Af, Ba[kt][nt], acc[nt], 0, 0, 0); \
            _Pragma("unroll")                                                   \
            for (int nt = 0; nt < 4; ++nt)                                      \
                acc[8 + nt] = __builtin_amdgcn_mfma_f32_16x16x32_bf16(Af, Bv[kt][nt], acc[8 + nt], 0, 0, 0); \
        }                                                                       \
        if (quad == 0) {                                                        \
            _Pragma("unroll")                                                   \
            for (int nt = 0; nt < 12; ++nt)                                     \
                gh[wave * 192 + nt * 16 + l15] = acc[nt][0];                    \
        }                                                                       \
    }

// ---------------------------------------------------------------------------
// Token bidirectional GRU scan, BATCH-SPLIT: blocks 0..15 = (batch b, dir),
// each scans ONE batch lane (GRU recurrence is batch-independent).
// Per-step per-CU cost: MFMA count unchanged (M-tile=16 floor) but gate VALU,
// gi loads, gh LDS traffic and stores all shrink 8x -> step approaches the
// MFMA-issue + barrier floor. Blocks 16..255 zero-fill d_out.
__global__ __attribute__((amdgpu_flat_work_group_size(256, 256), amdgpu_waves_per_eu(1, 1)))
void token_scan_zero(
    const unsigned short* __restrict__ gi_f, const unsigned short* __restrict__ gi_r,
    const unsigned short* __restrict__ Wh_fc, const unsigned short* __restrict__ Wh_rc,
    const void* __restrict__ bh_f, const void* __restrict__ bh_r,
    unsigned short* __restrict__ outp, void* __restrict__ dout,
    const void* __restrict__ emb) {

    const int f32 = detect_f32(emb);

    if (blockIdx.x >= 16) {
        uint4 z = {0u, 0u, 0u, 0u};
        uint4* p = (uint4*)dout;
        const size_t nvec = OUT_ELEMS * (f32 ? 4 : 2) / 16;
        size_t stride = (size_t)(gridDim.x - 16) * 256;
        for (size_t v = (size_t)(blockIdx.x - 16) * 256 + threadIdx.x; v < nvec; v += stride)
            p[v] = z;
        return;
    }

    const int dir = blockIdx.x & 1;
    const int b   = blockIdx.x >> 1;
    __shared__ float gh[G3];
    __shared__ __align__(16) unsigned short hb[16 * HBSTR];
    __shared__ float bhs[G3];

    const int tid = threadIdx.x;
    const int wave = tid >> 6, lane = tid & 63;
    const int l15 = lane & 15, quad = lane >> 4;

    const unsigned short* Whc = dir ? Wh_rc : Wh_fc;
    const void* bh = dir ? bh_r : bh_f;
    const unsigned short* gi = dir ? gi_r : gi_f;

    LOAD_BFRAGS(Whc)

    for (int e = tid; e < 16 * HBSTR; e += 256) hb[e] = 0;    // h0 = 0, pads 0
    for (int c2 = tid; c2 < G3; c2 += 256) bhs[c2] = lds1(bh, c2, f32);
    float hreg = 0.f;
    __syncthreads();

    const int c = tid;
    for (int t = 0; t < NN; ++t) {
        const int row = dir ? (NN - 1 - t) : t;
        // prefetch gi row for our batch (independent of MFMA phase)
        const unsigned short* gp = gi + (size_t)row * BB * G3 + (size_t)b * G3;
        unsigned short g0 = gp[c], g1 = gp[c + 256], g2 = gp[c + 512];
        MFMA_GH_ROW0()
        __syncthreads();
        float rr = sigm(bf2f(g0) + gh[c] + bhs[c]);
        float zz = sigm(bf2f(g1) + gh[c + 256] + bhs[c + 256]);
        float nn = tanh_fast(bf2f(g2) + rr * (gh[c + 512] + bhs[c + 512]));
        float hn = (1.f - zz) * nn + zz * hreg;
        hreg = hn;
        hb[c] = f2bf(hn);                                     // row 0 of A-tile
        __syncthreads();
        // deferred global store (no pending vmem at the barrier above)
        outp[((size_t)(row * BB + b)) * 512 + dir * 256 + c] = f2bf(hreg);
    }
}

// ---------------------------------------------------------------------------
// Segment GRU scans: 256 blocks = (start i0, dir), 256 threads, 1 block/CU.
__global__ __attribute__((amdgpu_flat_work_group_size(256, 256), amdgpu_waves_per_eu(1, 1)))
void seg_scan(
    const unsigned short* __restrict__ gi,     // gi_s bf16 ws (1024 x 768)
    const unsigned short* __restrict__ Whc,    // Wh_s bf16 ws
    const void* __restrict__ bh,
    const void* __restrict__ h0f, const void* __restrict__ h0b,
    void* __restrict__ dout, const void* __restrict__ emb) {

    const int f32 = detect_f32(emb);

    __shared__ float gh[BB][G3];
    __shared__ __align__(16) unsigned short hb[16 * HBSTR];
    __shared__ float bhs[G3];

    const int tid = threadIdx.x;
    const int wave = tid >> 6, lane = tid & 63;
    const int l15 = lane & 15, quad = lane >> 4;
    const int dir = blockIdx.x & 1, i0 = blockIdx.x >> 1;

    LOAD_BFRAGS(Whc)

    const void* h0 = dir ? h0b : h0f;
    const size_t h0base = (size_t)i0 * (BB * SS);
    const int c = tid;
    float hreg[BB];
#pragma unroll
    for (int b = 0; b < BB; ++b) {
        float v = lds1(h0, h0base + b * 256 + c, f32);
        hreg[b] = v;
        hb[b * HBSTR + c] = f2bf(v);
    }
    for (int e = 8 * HBSTR + tid; e < 16 * HBSTR; e += 256) hb[e] = 0;
    for (int c2 = tid; c2 < G3; c2 += 256) bhs[c2] = lds1(bh, c2, f32);
    __syncthreads();

    const int nsteps = dir ? min(TT, i0 + 1) : min(TT, NN - i0);
    for (int t = 0; t < nsteps; ++t) {
        const int j = dir ? (i0 - t) : (i0 + t);
        unsigned short gpre[BB][3];
        const unsigned short* gp = gi + (size_t)j * BB * G3;
#pragma unroll
        for (int b = 0; b < BB; ++b) {
            gpre[b][0] = gp[b * G3 + c];
            gpre[b][1] = gp[b * G3 + c + 256];
            gpre[b][2] = gp[b * G3 + c + 512];
        }
        MFMA_GH()
        __syncthreads();

#pragma unroll
        for (int b = 0; b < BB; ++b) {
            float rr = sigm(bf2f(gpre[b][0]) + gh[b][c] + bhs[c]);
            float zz = sigm(bf2f(gpre[b][1]) + gh[b][c + 256] + bhs[c + 256]);
            float nn = tanh_fast(bf2f(gpre[b][2]) + rr * (gh[b][c + 512] + bhs[c + 512]));
            float hn = (1.f - zz) * nn + zz * hreg[b];
            hreg[b] = hn;
            hb[b * HBSTR + c] = f2bf(hn);
        }
        __syncthreads();

        // deferred global stores (issued after the barrier)
        const int r0 = dir ? j : i0;                 // triu pair (r0,c0), c0-r0=t
        const size_t tri = (size_t)r0 * NN - (size_t)(r0 * (r0 - 1)) / 2 + t;
        const size_t obase = tri * (BB * 512) + (dir ? 256 : 0);
#pragma unroll
        for (int b = 0; b < BB; ++b) {
            outw(dout, obase + b * 512 + c, hreg[b], f32);
            if (i0 == NN - 1) {
                if (dir == 0 && t == 0)      outw(dout, HIDOFF + b * 512 + c, hreg[b], f32);
                if (dir == 1 && t == TT - 1) outw(dout, HIDOFF + 256 + b * 512 + c, hreg[b], f32);
            }
        }
    }
}

// ---------------------------------------------------------------------------
extern "C" void kernel_launch(void* const* d_in, const int* in_sizes, int n_in,
                              void* d_out, int out_size, void* d_ws, size_t ws_size,
                              hipStream_t stream) {
    const int* tokens = (const int*)d_in[0];
    const void* emb   = d_in[1];
    const void* Wi_f  = d_in[2];
    const void* Wh_f  = d_in[3];
    const void* bi_f  = d_in[4];
    const void* bh_f  = d_in[5];
    const void* Wi_r  = d_in[6];
    const void* Wh_r  = d_in[7];
    const void* bi_r  = d_in[8];
    const void* bh_r  = d_in[9];
    const void* Wi_s  = d_in[10];
    const void* Wh_s  = d_in[11];
    const void* bi_s  = d_in[12];
    const void* bh_s  = d_in[13];
    const void* h0f   = d_in[14];
    const void* h0b   = d_in[15];

    unsigned short* wsu = (unsigned short*)d_ws;
    unsigned short* gif  = wsu;                 // 786432 halves (1.5 MB)
    unsigned short* gir  = wsu + 786432;        // 786432
    unsigned short* outp = wsu + 1572864;       // 524288 (1 MB)
    unsigned short* wcv  = wsu + 2097152;       // 1376256 (2.625 MB)
    unsigned short* gis  = gif;                 // alias (gif dead after token scan)
    // peak ws = 6.63 MB

    const unsigned short* Wi_fc = wcv;
    const unsigned short* Wi_rc = wcv + 196608;
    const unsigned short* Wh_fc = wcv + 393216;
    const unsigned short* Wh_rc = wcv + 589824;
    const unsigned short* Wh_sc = wcv + 786432;
    const unsigned short* Wi_sc = wcv + 983040;

    conv_all<<<dim3(672), dim3(256), 0, stream>>>(Wi_f, Wi_r, Wh_f, Wh_r, Wh_s, Wi_s,
                                                  wcv, emb);
    gemm_mfma<256><<<dim3(256), dim3(256), 0, stream>>>(
        tokens, emb, Wi_fc, bi_f, gif, Wi_rc, bi_r, gir, emb);
    token_scan_zero<<<dim3(256), dim3(256), 0, stream>>>(gif, gir, Wh_fc, Wh_rc,
                                                         bh_f, bh_r, outp, d_out, emb);
    gemm_mfma<512><<<dim3(128), dim3(256), 0, stream>>>(
        nullptr, outp, Wi_sc, bi_s, gis, nullptr, nullptr, nullptr, emb);
    seg_scan<<<dim3(256), dim3(256), 0, stream>>>(gis, Wh_sc, bh_s, h0f, h0b, d_out, emb);
}

// Round 2
// 501.593 us; speedup vs baseline: 1.3331x; 1.0459x over previous
//
#include <hip/hip_runtime.h>
#include <cstdint>
#include <cstddef>

// Problem constants
#define NN 128   // seq len
#define BB 8     // batch
#define EE 256   // embed
#define HH 256   // hidden
#define SS 256   // segment dim
#define TT 32    // segment threshold
#define G3 768   // 3*H = 3*S
#define HBSTR 264           // LDS bf16 h row stride (pad 256->264)
#define HIDOFF 33816576ull  // 8256*8*512, start of `hidden` in d_out (elements)
#define OUT_ELEMS 33820672ull

typedef __attribute__((ext_vector_type(8))) short bf16x8;
typedef __attribute__((ext_vector_type(4))) float f32x4;
typedef _Float16 f16;
typedef __attribute__((ext_vector_type(2))) _Float16 f16x2;

__device__ __forceinline__ float bf2f(unsigned short u) {
    union { unsigned u; float f; } v; v.u = ((unsigned)u) << 16; return v.f;
}
__device__ __forceinline__ unsigned short f2bf(float f) {
    union { float f; unsigned u; } v; v.f = f;
    unsigned r = v.u + 0x7fffu + ((v.u >> 16) & 1u);   // RNE
    return (unsigned short)(r >> 16);
}
__device__ __forceinline__ unsigned short f2h(float f) {
    union { f16 h; unsigned short u; } v; v.h = (f16)f; return v.u;
}
__device__ __forceinline__ float dot2h(unsigned wu, unsigned hu, float acc) {
    union { unsigned u; f16x2 h; } a, b2;
    a.u = wu; b2.u = hu;
    return __builtin_amdgcn_fdot2(a.h, b2.h, acc, false);
}
__device__ __forceinline__ float rcpf(float x) { return __builtin_amdgcn_rcpf(x); }
__device__ __forceinline__ float sigm(float x) { return rcpf(1.f + __expf(-x)); }
__device__ __forceinline__ float tanh_fast(float x) {
    float xc = fminf(fmaxf(x, -10.f), 10.f);
    float e2 = __expf(2.f * xc);
    return (e2 - 1.f) * rcpf(e2 + 1.f);
}

// fp32-vs-bf16 physical layout detector (round-2 counters: fp32 confirmed).
__device__ __forceinline__ int detect_f32(const void* emb) {
    const unsigned* w = (const unsigned*)emb;
    int bad = 0;
    for (int i = 0; i < 128; ++i) {
        unsigned u = w[i];
        bad |= (((u >> 7)  & 0xFFu) >= 0xC8u);
        bad |= (((u >> 23) & 0xFFu) >= 0xC8u);
    }
    return bad;
}
__device__ __forceinline__ float lds1(const void* p, size_t i, int f32) {
    return f32 ? ((const float*)p)[i] : bf2f(((const unsigned short*)p)[i]);
}
__device__ __forceinline__ void outw(void* p, size_t i, float v, int f32) {
    if (f32) ((float*)p)[i] = v;
    else ((unsigned short*)p)[i] = f2bf(v);
}

// ---------------------------------------------------------------------------
// One-shot weight conversion in ws. Layout (ushort offsets):
// Wi_f 0, Wi_r 196608 (bf16), Wh_f 393216, Wh_r 589824 (FP16 for dot-scan!),
// Wh_s 786432, Wi_s 983040 (bf16).
__global__ __launch_bounds__(256) void conv_all(
    const void* __restrict__ Wi_f, const void* __restrict__ Wi_r,
    const void* __restrict__ Wh_f, const void* __restrict__ Wh_r,
    const void* __restrict__ Wh_s, const void* __restrict__ Wi_s,
    unsigned short* __restrict__ dst, const void* __restrict__ emb) {
    const int f32 = detect_f32(emb);
    size_t i = ((size_t)blockIdx.x * 256 + threadIdx.x) * 8;   // grid 672 blocks
    const void* src; size_t off; int h16 = 0;
    if      (i < 196608)  { src = Wi_f; off = i; }
    else if (i < 393216)  { src = Wi_r; off = i - 196608; }
    else if (i < 589824)  { src = Wh_f; off = i - 393216; h16 = 1; }
    else if (i < 786432)  { src = Wh_r; off = i - 589824; h16 = 1; }
    else if (i < 983040)  { src = Wh_s; off = i - 786432; }
    else                  { src = Wi_s; off = i - 983040; }
    bf16x8 v;
    if (f32) {
        const float* q = (const float*)src + off;
        float4 a = *(const float4*)q, b4 = *(const float4*)(q + 4);
        float f[8] = {a.x, a.y, a.z, a.w, b4.x, b4.y, b4.z, b4.w};
#pragma unroll
        for (int j = 0; j < 8; ++j)
            v[j] = (short)(h16 ? f2h(f[j]) : f2bf(f[j]));
    } else {
        v = *(const bf16x8*)((const unsigned short*)src + off);
        if (h16) {
#pragma unroll
            for (int j = 0; j < 8; ++j)
                v[j] = (short)f2h(bf2f((unsigned short)v[j]));
        }
    }
    *(bf16x8*)(dst + i) = v;
}

// ---------------------------------------------------------------------------
// MFMA GEMM, W pre-converted bf16. C bf16. A: token-gather (emb) or bf16 ws.
template <int KK>
__global__ __launch_bounds__(256) void gemm_mfma(
    const int* __restrict__ tok, const void* __restrict__ Asrc,
    const unsigned short* __restrict__ W,  const void* __restrict__ bias,
    unsigned short* __restrict__ C,
    const unsigned short* __restrict__ W2, const void* __restrict__ bias2,
    unsigned short* __restrict__ C2, const void* __restrict__ emb) {

    const int f32 = detect_f32(emb);
    __shared__ unsigned short As[64 * 260];

    int bid = blockIdx.x;
    const unsigned short* Wp = W; const void* bp = bias; unsigned short* Cp = C;
    if (C2 && bid >= 128) { bid -= 128; Wp = W2; bp = bias2; Cp = C2; }
    const int mb = bid >> 3, nb = bid & 7;

    const int tid = threadIdx.x, wave = tid >> 6, lane = tid & 63;
    const int l15 = lane & 15, quad = lane >> 4;

    f32x4 acc[6];
#pragma unroll
    for (int nt = 0; nt < 6; ++nt) acc[nt] = (f32x4){0.f, 0.f, 0.f, 0.f};

    for (int kh = 0; kh < KK; kh += 256) {
        __syncthreads();
        for (int e = tid * 4; e < 64 * 256; e += 1024) {
            int r = e >> 8, k = e & 255;
            int gr = mb * 64 + r;
            unsigned short h4[4];
            if (tok) {
                size_t arow = (size_t)tok[gr] * EE + kh + k;
                if (f32) {
                    float4 v = *(const float4*)((const float*)Asrc + arow);
                    h4[0] = f2bf(v.x); h4[1] = f2bf(v.y); h4[2] = f2bf(v.z); h4[3] = f2bf(v.w);
                } else {
                    *(uint2*)h4 = *(const uint2*)((const unsigned short*)Asrc + arow);
                }
            } else {
                *(uint2*)h4 = *(const uint2*)((const unsigned short*)Asrc + (size_t)gr * KK + kh + k);
            }
            *(uint2*)(As + r * 260 + k) = *(uint2*)h4;
        }
        __syncthreads();
#pragma unroll
        for (int kt = 0; kt < 8; ++kt) {
            bf16x8 Af = *(const bf16x8*)(As + (wave * 16 + l15) * 260 + kt * 32 + quad * 8);
#pragma unroll
            for (int nt = 0; nt < 6; ++nt) {
                int col = nb * 96 + nt * 16 + l15;
                bf16x8 Bfr = *(const bf16x8*)(Wp + (size_t)col * KK + kh + kt * 32 + quad * 8);
                acc[nt] = __builtin_amdgcn_mfma_f32_16x16x32_bf16(Af, Bfr, acc[nt], 0, 0, 0);
            }
        }
    }
#pragma unroll
    for (int nt = 0; nt < 6; ++nt) {
        int col = nb * 96 + nt * 16 + l15;
        float bv = lds1(bp, col, f32);
#pragma unroll
        for (int r4 = 0; r4 < 4; ++r4) {
            int row = mb * 64 + wave * 16 + quad * 4 + r4;
            Cp[(size_t)row * G3 + col] = f2bf(acc[nt][r4] + bv);
        }
    }
}

// ---------------------------------------------------------------------------
// Scan machinery for seg_scan (MFMA path; M=8/16 rows used, still beats VALU).
#define LOAD_BFRAGS(Whc)                                                        \
    bf16x8 Ba[8][8]; bf16x8 Bv[8][4];                                           \
    _Pragma("unroll")                                                           \
    for (int nt = 0; nt < 12; ++nt) {                                           \
        int col = wave * 192 + nt * 16 + l15;                                   \
        _Pragma("unroll")                                                       \
        for (int kt = 0; kt < 8; ++kt) {                                        \
            bf16x8 f = *(const bf16x8*)(Whc + (size_t)col * 256 + kt * 32 + quad * 8); \
            if (nt < 8) Ba[kt][nt] = f; else Bv[kt][nt - 8] = f;                \
        }                                                                       \
    }                                                                           \
    _Pragma("unroll")                                                           \
    for (int kt = 0; kt < 8; ++kt) {                                            \
        _Pragma("unroll")                                                       \
        for (int nt = 0; nt < 8; ++nt) asm volatile("" : "+a"(Ba[kt][nt]));     \
        _Pragma("unroll")                                                       \
        for (int nt = 0; nt < 4; ++nt) asm volatile("" : "+v"(Bv[kt][nt]));     \
    }

// Full 8-batch variant (seg_scan): writes gh rows 0..7.
#define MFMA_GH()                                                               \
    {                                                                           \
        f32x4 acc[12];                                                          \
        _Pragma("unroll")                                                       \
        for (int nt = 0; nt < 12; ++nt) acc[nt] = (f32x4){0.f, 0.f, 0.f, 0.f};  \
        _Pragma("unroll")                                                       \
        for (int kt = 0; kt < 8; ++kt) {                                        \
            bf16x8 Af = *(const bf16x8*)(hb + l15 * HBSTR + kt * 32 + quad * 8);\
            _Pragma("unroll")                                                   \
            for (int nt = 0; nt < 8; ++nt)                                      \
                acc[nt] = __builtin_amdgcn_mfma_f32_16x16x32_bf16(Af, Ba[kt][nt], acc[nt], 0, 0, 0); \
            _Pragma("unroll")                                                   \
            for (int nt = 0; nt < 4; ++nt)                                      \
                acc[8 + nt] = __builtin_amdgcn_mfma_f32_16x16x32_bf16(Af, Bv[kt][nt], acc[8 + nt], 0, 0, 0); \
        }                                                                       \
        if (quad < 2) {                                                         \
            _Pragma("unroll")                                                   \
            for (int nt = 0; nt < 12; ++nt) {                                   \
                int col = wave * 192 + nt * 16 + l15;                           \
                _Pragma("unroll")                                               \
                for (int r4 = 0; r4 < 4; ++r4) gh[quad * 4 + r4][col] = acc[nt][r4]; \
            }                                                                   \
        }                                                                       \
    }

// ---------------------------------------------------------------------------
// Token bidirectional GRU scan, VALU-dot formulation.
// gh = Wh(768x256) @ h is a matvec (393 KFLOP/step); the MFMA path wasted
// 15/16 M-rows (~1860 cyc/step/SIMD). v_dot2_f32_f16 on the vector pipe:
// 256 MAC/cyc/CU -> 768 cyc/step floor. 512 thr = (col c, K-half kh); weights
// stay register-resident (192 dwords fp16 pairs) across all 128 steps; h is
// broadcast from 512 B LDS (uniform-addr ds_read_b128, conflict-free);
// K-halves combine through a 3 KB LDS partial. Blocks 16..255 zero-fill.
__global__ __attribute__((amdgpu_flat_work_group_size(512, 512), amdgpu_waves_per_eu(2, 2)))
void token_scan_zero(
    const unsigned short* __restrict__ gi_f, const unsigned short* __restrict__ gi_r,
    const unsigned short* __restrict__ Wh_fh, const unsigned short* __restrict__ Wh_rh,
    const void* __restrict__ bh_f, const void* __restrict__ bh_r,
    unsigned short* __restrict__ outp, void* __restrict__ dout,
    const void* __restrict__ emb) {

    const int f32 = detect_f32(emb);

    if (blockIdx.x >= 16) {
        uint4 z = {0u, 0u, 0u, 0u};
        uint4* p = (uint4*)dout;
        const size_t nvec = OUT_ELEMS * (f32 ? 4 : 2) / 16;
        size_t stride = (size_t)(gridDim.x - 16) * 512;
        for (size_t v = (size_t)(blockIdx.x - 16) * 512 + threadIdx.x; v < nvec; v += stride)
            p[v] = z;
        return;
    }

    const int dir = blockIdx.x & 1;
    const int b   = blockIdx.x >> 1;
    const int tid = threadIdx.x;
    const int c = tid & 255, kh = tid >> 8;       // kh: K-half (wave-uniform)

    __shared__ __align__(16) unsigned short hbs[256];   // h as fp16
    __shared__ float pr[3][256];                        // khalf1 partial sums

    const unsigned short* Wh = dir ? Wh_rh : Wh_fh;     // fp16 content
    const unsigned short* gi = dir ? gi_r : gi_f;
    const void* bh = dir ? bh_r : bh_f;

    // Register-resident weights: 3 gates x 64 dwords (fp16 pairs) of our K-half.
    unsigned w[192];
#pragma unroll
    for (int g = 0; g < 3; ++g) {
        const unsigned* wp = (const unsigned*)(Wh + (size_t)(g * 256 + c) * 256 + kh * 128);
#pragma unroll
        for (int q = 0; q < 16; ++q) {
            uint4 v = *(const uint4*)(wp + q * 4);
            w[g * 64 + q * 4 + 0] = v.x; w[g * 64 + q * 4 + 1] = v.y;
            w[g * 64 + q * 4 + 2] = v.z; w[g * 64 + q * 4 + 3] = v.w;
        }
    }
    const float bh0 = lds1(bh, c, f32);
    const float bh1 = lds1(bh, c + 256, f32);
    const float bh2 = lds1(bh, c + 512, f32);

    if (tid < 256) hbs[tid] = 0;                  // h0 = 0 (fp16 zero bits)
    float hreg = 0.f;
    __syncthreads();

    const unsigned* hbw = (const unsigned*)hbs + kh * 64;
    for (int t = 0; t < NN; ++t) {
        const int row = dir ? (NN - 1 - t) : t;
        unsigned short g0 = 0, g1 = 0, g2 = 0;
        if (kh == 0) {                            // gi prefetch (gate half only)
            const unsigned short* gp = gi + (size_t)row * BB * G3 + (size_t)b * G3;
            g0 = gp[c]; g1 = gp[c + 256]; g2 = gp[c + 512];
        }
        float a0 = 0.f, a1 = 0.f, a2 = 0.f;
#pragma unroll
        for (int q = 0; q < 16; ++q) {
            uint4 hv = *(const uint4*)(hbw + q * 4);   // uniform-addr broadcast
            a0 = dot2h(w[      q * 4 + 0], hv.x, a0);
            a0 = dot2h(w[      q * 4 + 1], hv.y, a0);
            a0 = dot2h(w[      q * 4 + 2], hv.z, a0);
            a0 = dot2h(w[      q * 4 + 3], hv.w, a0);
            a1 = dot2h(w[ 64 + q * 4 + 0], hv.x, a1);
            a1 = dot2h(w[ 64 + q * 4 + 1], hv.y, a1);
            a1 = dot2h(w[ 64 + q * 4 + 2], hv.z, a1);
            a1 = dot2h(w[ 64 + q * 4 + 3], hv.w, a1);
            a2 = dot2h(w[128 + q * 4 + 0], hv.x, a2);
            a2 = dot2h(w[128 + q * 4 + 1], hv.y, a2);
            a2 = dot2h(w[128 + q * 4 + 2], hv.z, a2);
            a2 = dot2h(w[128 + q * 4 + 3], hv.w, a2);
        }
        if (kh) { pr[0][c] = a0; pr[1][c] = a1; pr[2][c] = a2; }
        __syncthreads();
        if (kh == 0) {
            a0 += pr[0][c]; a1 += pr[1][c]; a2 += pr[2][c];
            float rr = sigm(bf2f(g0) + a0 + bh0);
            float zz = sigm(bf2f(g1) + a1 + bh1);
            float nn = tanh_fast(bf2f(g2) + rr * (a2 + bh2));
            float hn = (1.f - zz) * nn + zz * hreg;
            hreg = hn;
            hbs[c] = f2h(hn);
        }
        __syncthreads();
        if (kh == 0)                              // deferred store (drains next bar)
            outp[((size_t)(row * BB + b)) * 512 + dir * 256 + c] = f2bf(hreg);
    }
}

// ---------------------------------------------------------------------------
// Segment GRU scans: 256 blocks = (start i0, dir), 256 threads, 1 block/CU.
__global__ __attribute__((amdgpu_flat_work_group_size(256, 256), amdgpu_waves_per_eu(1, 1)))
void seg_scan(
    const unsigned short* __restrict__ gi,     // gi_s bf16 ws (1024 x 768)
    const unsigned short* __restrict__ Whc,    // Wh_s bf16 ws
    const void* __restrict__ bh,
    const void* __restrict__ h0f, const void* __restrict__ h0b,
    void* __restrict__ dout, const void* __restrict__ emb) {

    const int f32 = detect_f32(emb);

    __shared__ float gh[BB][G3];
    __shared__ __align__(16) unsigned short hb[16 * HBSTR];

    const int tid = threadIdx.x;
    const int wave = tid >> 6, lane = tid & 63;
    const int l15 = lane & 15, quad = lane >> 4;
    const int dir = blockIdx.x & 1, i0 = blockIdx.x >> 1;

    LOAD_BFRAGS(Whc)

    const void* h0 = dir ? h0b : h0f;
    const size_t h0base = (size_t)i0 * (BB * SS);
    const int c = tid;
    // loop-invariant bias in registers (was per-step LDS reads)
    const float bh0 = lds1(bh, c, f32);
    const float bh1 = lds1(bh, c + 256, f32);
    const float bh2 = lds1(bh, c + 512, f32);
    float hreg[BB];
#pragma unroll
    for (int b = 0; b < BB; ++b) {
        float v = lds1(h0, h0base + b * 256 + c, f32);
        hreg[b] = v;
        hb[b * HBSTR + c] = f2bf(v);
    }
    for (int e = 8 * HBSTR + tid; e < 16 * HBSTR; e += 256) hb[e] = 0;
    __syncthreads();

    const int nsteps = dir ? min(TT, i0 + 1) : min(TT, NN - i0);
    for (int t = 0; t < nsteps; ++t) {
        const int j = dir ? (i0 - t) : (i0 + t);
        unsigned short gpre[BB][3];
        const unsigned short* gp = gi + (size_t)j * BB * G3;
#pragma unroll
        for (int b = 0; b < BB; ++b) {
            gpre[b][0] = gp[b * G3 + c];
            gpre[b][1] = gp[b * G3 + c + 256];
            gpre[b][2] = gp[b * G3 + c + 512];
        }
        MFMA_GH()
        __syncthreads();

#pragma unroll
        for (int b = 0; b < BB; ++b) {
            float rr = sigm(bf2f(gpre[b][0]) + gh[b][c] + bh0);
            float zz = sigm(bf2f(gpre[b][1]) + gh[b][c + 256] + bh1);
            float nn = tanh_fast(bf2f(gpre[b][2]) + rr * (gh[b][c + 512] + bh2));
            float hn = (1.f - zz) * nn + zz * hreg[b];
            hreg[b] = hn;
            hb[b * HBSTR + c] = f2bf(hn);
        }
        __syncthreads();

        // deferred global stores (issued after the barrier)
        const int r0 = dir ? j : i0;                 // triu pair (r0,c0), c0-r0=t
        const size_t tri = (size_t)r0 * NN - (size_t)(r0 * (r0 - 1)) / 2 + t;
        const size_t obase = tri * (BB * 512) + (dir ? 256 : 0);
#pragma unroll
        for (int b = 0; b < BB; ++b) {
            outw(dout, obase + b * 512 + c, hreg[b], f32);
            if (i0 == NN - 1) {
                if (dir == 0 && t == 0)      outw(dout, HIDOFF + b * 512 + c, hreg[b], f32);
                if (dir == 1 && t == TT - 1) outw(dout, HIDOFF + 256 + b * 512 + c, hreg[b], f32);
            }
        }
    }
}

// ---------------------------------------------------------------------------
extern "C" void kernel_launch(void* const* d_in, const int* in_sizes, int n_in,
                              void* d_out, int out_size, void* d_ws, size_t ws_size,
                              hipStream_t stream) {
    const int* tokens = (const int*)d_in[0];
    const void* emb   = d_in[1];
    const void* Wi_f  = d_in[2];
    const void* Wh_f  = d_in[3];
    const void* bi_f  = d_in[4];
    const void* bh_f  = d_in[5];
    const void* Wi_r  = d_in[6];
    const void* Wh_r  = d_in[7];
    const void* bi_r  = d_in[8];
    const void* bh_r  = d_in[9];
    const void* Wi_s  = d_in[10];
    const void* Wh_s  = d_in[11];
    const void* bi_s  = d_in[12];
    const void* bh_s  = d_in[13];
    const void* h0f   = d_in[14];
    const void* h0b   = d_in[15];

    unsigned short* wsu = (unsigned short*)d_ws;
    unsigned short* gif  = wsu;                 // 786432 halves (1.5 MB)
    unsigned short* gir  = wsu + 786432;        // 786432
    unsigned short* outp = wsu + 1572864;       // 524288 (1 MB)
    unsigned short* wcv  = wsu + 2097152;       // 1376256 (2.625 MB)
    unsigned short* gis  = gif;                 // alias (gif dead after token scan)
    // peak ws = 6.63 MB

    const unsigned short* Wi_fc = wcv;
    const unsigned short* Wi_rc = wcv + 196608;
    const unsigned short* Wh_fh = wcv + 393216;   // fp16 content (dot scan)
    const unsigned short* Wh_rh = wcv + 589824;   // fp16 content (dot scan)
    const unsigned short* Wh_sc = wcv + 786432;
    const unsigned short* Wi_sc = wcv + 983040;

    conv_all<<<dim3(672), dim3(256), 0, stream>>>(Wi_f, Wi_r, Wh_f, Wh_r, Wh_s, Wi_s,
                                                  wcv, emb);
    gemm_mfma<256><<<dim3(256), dim3(256), 0, stream>>>(
        tokens, emb, Wi_fc, bi_f, gif, Wi_rc, bi_r, gir, emb);
    token_scan_zero<<<dim3(256), dim3(512), 0, stream>>>(gif, gir, Wh_fh, Wh_rh,
                                                         bh_f, bh_r, outp, d_out, emb);
    gemm_mfma<512><<<dim3(128), dim3(256), 0, stream>>>(
        nullptr, outp, Wi_sc, bi_s, gis, nullptr, nullptr, nullptr, emb);
    seg_scan<<<dim3(256), dim3(256), 0, stream>>>(gis, Wh_sc, bh_s, h0f, h0b, d_out, emb);
}